// Round 10
// baseline (227.954 us; speedup 1.0000x reference)
//
#include <hip/hip_runtime.h>

// Attention block: qkv proj -> RoPE -> causal GQA flash attention -> out proj.
// B=1, S=2048, H=2048, NH=32, KVH=8, D=64, G=4.
// R10: R9 with the PSTR bug fixed. PSTR must be >= 64 (Ps rows hold 64 keys);
//     56 truncated rows -> aliasing (R9's absmax 0.43). Back to 72 (also the
//     good bank rotation: byte stride 144 -> bank c*4+...). Keeps R9's wins:
//     row-sum l via ones-MFMA (accl), exp2 with q pre-scaled by log2(e)/8.

typedef __bf16 bf16_t;
typedef __attribute__((ext_vector_type(8))) __bf16 bf16x8;
typedef __attribute__((ext_vector_type(4))) __bf16 bf16x4;
typedef __attribute__((ext_vector_type(4))) float f32x4;

#define S_LEN 2048
#define H_DIM 2048
#define NHEAD 32
#define KVH 8
#define HD 64
#define QKV_N 3072  // (NH + 2*KVH) * D

#define ENT_STRIDE 8320   // floats per partial entry: 4h*32r*64d + 4h*32r l
#define QSCALE 0.18033688f   // (1/8) * log2(e): softmax scale folded with exp2 conversion
#define EBIAS  11.541560f    // 8 * log2(e): exp(s-8) == exp2(st - EBIAS) with st = s*log2e

// ---------------- fused cast fp32 -> bf16 (x, w_qkv, w_o) ----------------
__global__ void cast3_kernel(const float* __restrict__ x, const float* __restrict__ wq,
                             const float* __restrict__ wo, bf16_t* __restrict__ xb,
                             bf16_t* __restrict__ wqb, bf16_t* __restrict__ wob) {
  int i = blockIdx.x * blockDim.x + threadIdx.x;
  const int n1 = S_LEN * H_DIM / 4, n2 = QKV_N * H_DIM / 4, n3 = H_DIM * H_DIM / 4;
  const float* src; bf16_t* dst; int j;
  if (i < n1)           { src = x;  dst = xb;  j = i; }
  else if (i < n1 + n2) { src = wq; dst = wqb; j = i - n1; }
  else if (i < n1 + n2 + n3) { src = wo; dst = wob; j = i - n1 - n2; }
  else return;
  float4 v = ((const float4*)src)[j];
  bf16x4 o;
  o.x = (bf16_t)v.x; o.y = (bf16_t)v.y; o.z = (bf16_t)v.z; o.w = (bf16_t)v.w;
  ((bf16x4*)dst)[j] = o;
}

// ---------------- async 16B global -> LDS ----------------
__device__ __forceinline__ void async_copy16(bf16_t* lds_base, const bf16_t* g) {
  __builtin_amdgcn_global_load_lds(
      (const __attribute__((address_space(1))) unsigned int*)g,
      (__attribute__((address_space(3))) unsigned int*)lds_base, 16, 0, 0);
}

// ---------------- GEMM: C[M,N] = A[M,K] * B[N,K]^T (bf16 in) ----------------
// 128x128 tile, 512 threads = 8 waves. Wave-pair (wq, wq+4) owns one 64x64
// C-subtile; group gw=w>>2 does K32-half gw of each BK=64 iter. Double-buffered
// staging, 1 raw barrier + vmcnt(0)/iter. Partials combined via LDS at end.
#define GBM 128
#define GBN 128

template <int EPI>
__global__ __launch_bounds__(512, 4) void gemm_sk(const bf16_t* __restrict__ A,
                                                  const bf16_t* __restrict__ B,
                                                  float* __restrict__ C,
                                                  bf16_t* __restrict__ qb,
                                                  bf16_t* __restrict__ ktp,
                                                  bf16_t* __restrict__ vt2,
                                                  int M, int N, int K) {
  __shared__ __align__(16) bf16_t As[2][GBM * 64];
  __shared__ __align__(16) bf16_t Bs[2][GBM * 64];

  const int tid  = threadIdx.x;
  const int lane = tid & 63;
  const int w    = tid >> 6;
  const int wq   = w & 3;
  const int gw   = w >> 2;
  const int wm   = (wq >> 1) * 64;
  const int wn   = (wq & 1) * 64;
  const int c    = lane & 15;
  const int quad = lane >> 4;
  const int m0   = blockIdx.y * GBM;
  const int n0   = blockIdx.x * GBN;

  f32x4 acc[4][4] = {};

  const bf16_t* Ab = A + (size_t)m0 * K;
  const bf16_t* Bb = B + (size_t)n0 * K;

  int srow[2], skc[2], sb[2];
#pragma unroll
  for (int i = 0; i < 2; ++i) {
    int p = i * 512 + tid;
    srow[i] = p >> 3;
    skc[i]  = (p & 7) ^ (srow[i] & 7);
    sb[i]   = (i * 512 + w * 64) * 8;
  }

  auto stage = [&](int buf, int k0) {
#pragma unroll
    for (int i = 0; i < 2; ++i) {
      async_copy16(&As[buf][sb[i]], Ab + (size_t)srow[i] * K + k0 + skc[i] * 8);
      async_copy16(&Bs[buf][sb[i]], Bb + (size_t)srow[i] * K + k0 + skc[i] * 8);
    }
  };

  auto compute = [&](int buf) {
    bf16x8 af[4], bfr[4];
#pragma unroll
    for (int mt = 0; mt < 4; ++mt) {
      int row = wm + mt * 16 + c;
      af[mt] = *(const bf16x8*)&As[buf][(row * 8 + ((gw * 4 + quad) ^ (row & 7))) * 8];
    }
#pragma unroll
    for (int nt = 0; nt < 4; ++nt) {
      int rowb = wn + nt * 16 + c;
      bfr[nt] = *(const bf16x8*)&Bs[buf][(rowb * 8 + ((gw * 4 + quad) ^ (rowb & 7))) * 8];
    }
#pragma unroll
    for (int mt = 0; mt < 4; ++mt)
#pragma unroll
      for (int nt = 0; nt < 4; ++nt)
        acc[mt][nt] = __builtin_amdgcn_mfma_f32_16x16x32_bf16(af[mt], bfr[nt], acc[mt][nt], 0, 0, 0);
  };

  const int NI = K >> 6;
  stage(0, 0);
  int buf = 0;
  for (int it = 0; it < NI; ++it) {
    asm volatile("s_waitcnt vmcnt(0)" ::: "memory");
    __builtin_amdgcn_s_barrier();
    if (it + 1 < NI) stage(buf ^ 1, (it + 1) << 6);
    compute(buf);
    buf ^= 1;
  }

  __syncthreads();
  float* xch = (float*)&As[0][0];
  if (gw == 1) {
#pragma unroll
    for (int t16 = 0; t16 < 16; ++t16)
      *(f32x4*)&xch[wq * 4096 + (t16 * 64 + lane) * 4] = acc[t16 >> 2][t16 & 3];
  }
  __syncthreads();
  if (gw == 0) {
#pragma unroll
    for (int t16 = 0; t16 < 16; ++t16) {
      f32x4 o = *(const f32x4*)&xch[wq * 4096 + (t16 * 64 + lane) * 4];
      acc[t16 >> 2][t16 & 3] += o;
    }

    if (EPI == 0) {
#pragma unroll
      for (int mt = 0; mt < 4; ++mt)
#pragma unroll
        for (int nt = 0; nt < 4; ++nt)
#pragma unroll
          for (int reg = 0; reg < 4; ++reg) {
            int row = m0 + wm + mt * 16 + quad * 4 + reg;
            int col = n0 + wn + nt * 16 + c;
            C[(size_t)row * N + col] = acc[mt][nt][reg];
          }
    } else {
      const int colb = n0 + wn;
      if (colb < NHEAD * HD) {
        const int h = colb >> 6;
#pragma unroll
        for (int nt = 0; nt < 2; ++nt) {
          const int i = nt * 16 + c;
          const float invf = __expf(-(float)i * (9.210340371976184f / 32.0f));
#pragma unroll
          for (int mt = 0; mt < 4; ++mt)
#pragma unroll
            for (int reg = 0; reg < 4; ++reg) {
              const int s = m0 + wm + mt * 16 + quad * 4 + reg;
              float sn, cs;
              __sincosf((float)s * invf, &sn, &cs);
              const float x1 = acc[mt][nt][reg], x2 = acc[mt][nt + 2][reg];
              bf16_t* q = qb + (size_t)s * H_DIM + h * HD;
              q[i]      = (bf16_t)((x1 * cs - x2 * sn) * QSCALE);
              q[i + 32] = (bf16_t)((x2 * cs + x1 * sn) * QSCALE);
            }
        }
      } else if (colb < NHEAD * HD + KVH * HD) {
        const int kh = (colb - NHEAD * HD) >> 6;
#pragma unroll
        for (int nt = 0; nt < 2; ++nt) {
          const int i = nt * 16 + c;
          const float invf = __expf(-(float)i * (9.210340371976184f / 32.0f));
#pragma unroll
          for (int mt = 0; mt < 4; ++mt)
#pragma unroll
            for (int reg = 0; reg < 4; ++reg) {
              const int s = m0 + wm + mt * 16 + quad * 4 + reg;
              float sn, cs;
              __sincosf((float)s * invf, &sn, &cs);
              const float x1 = acc[mt][nt][reg], x2 = acc[mt][nt + 2][reg];
              bf16_t* kd = ktp + ((size_t)kh * S_LEN + s) * HD;
              kd[i]      = (bf16_t)(x1 * cs - x2 * sn);
              kd[i + 32] = (bf16_t)(x2 * cs + x1 * sn);
            }
        }
      } else {
        const int kh = (colb - NHEAD * HD - KVH * HD) >> 6;
#pragma unroll
        for (int nt = 0; nt < 4; ++nt) {
          const int d = nt * 16 + c;
#pragma unroll
          for (int mt = 0; mt < 4; ++mt) {
            const int sr = m0 + wm + mt * 16 + quad * 4;
            bf16x4 pv;
#pragma unroll
            for (int reg = 0; reg < 4; ++reg) pv[reg] = (bf16_t)acc[mt][nt][reg];
            *(bf16x4*)&vt2[((size_t)kh * HD + d) * S_LEN + sr] = pv;
          }
        }
      }
    }
  }
}

// ---------------- split-K MFMA flash ----------------
// Work item e in [0,1280): kh=e/160; i=e%160 -> band b (chunks per qt = b+1).
// Band 0 (i<16): single chunk -> normalize and write attn directly.
// l via ones-MFMA: accl[rf][reg] = row-sum for qrow rf*16+quad*4+reg,
// replicated across c lanes -- matches acc layout exactly.
#define PSTR 72   // Ps row stride (bf16). MUST be >= 64 (row holds 64 keys)!
                  // 144B stride -> bank rotation c*4, write/read phases conflict-light.

__global__ __launch_bounds__(256) void flash_split(const bf16_t* __restrict__ qb,
                                                   const bf16_t* __restrict__ kt,
                                                   const bf16_t* __restrict__ vt2,
                                                   float* __restrict__ pbuf,
                                                   bf16_t* __restrict__ attn) {
  __shared__ __align__(16) bf16_t Ks[64 * 64];
  __shared__ __align__(16) bf16_t Vs[64 * 64];
  __shared__ __align__(16) bf16_t Ps[4][32 * PSTR];

  const int tid  = threadIdx.x;
  const int lane = tid & 63;
  const int w    = tid >> 6;
  const int e    = (int)gridDim.x - 1 - (int)blockIdx.x;
  const int kh   = e / 160;
  const int i    = e - kh * 160;

  int qt, t_begin, t_end;
  {
    int T;
    if (i < 16)      { qt = i;                T = (qt >> 1) + 1; t_begin = 0;                 t_end = T; }
    else if (i < 48) { int r = i - 16; qt = 16 + (r >> 1); int ck = r & 1;
                       T = (qt >> 1) + 1; t_begin = (ck * T) >> 1;      t_end = ((ck + 1) * T) >> 1; }
    else if (i < 96) { int r = i - 48; qt = 32 + r / 3;    int ck = r % 3;
                       T = (qt >> 1) + 1; t_begin = (ck * T) / 3;       t_end = ((ck + 1) * T) / 3; }
    else             { int r = i - 96; qt = 48 + (r >> 2); int ck = r & 3;
                       T = (qt >> 1) + 1; t_begin = (ck * T) >> 2;      t_end = ((ck + 1) * T) >> 2; }
  }
  const int T     = (qt >> 1) + 1;
  const int s0    = qt * 32;
  const int h     = kh * 4 + w;
  const int c     = lane & 15;
  const int quad  = lane >> 4;

  bf16x8 qf[2][2];
#pragma unroll
  for (int rf = 0; rf < 2; ++rf)
#pragma unroll
    for (int ks = 0; ks < 2; ++ks)
      qf[rf][ks] = *(const bf16x8*)(qb + (size_t)(s0 + rf * 16 + c) * H_DIM + h * HD + ks * 32 + quad * 8);

  bf16x8 onesf;
#pragma unroll
  for (int j = 0; j < 8; ++j) onesf[j] = (bf16_t)1.0f;

  f32x4 acc[2][4] = {};
  f32x4 accl[2]   = {};

  const bf16_t* kbase = kt + (size_t)kh * S_LEN * HD;
  const bf16_t* vbase = vt2 + (size_t)kh * HD * S_LEN;

  int srow[2], skc[2], sbase[2];
#pragma unroll
  for (int i2 = 0; i2 < 2; ++i2) {
    int chunkbase = i2 * 256 + w * 64;
    int p = chunkbase + lane;
    sbase[i2] = chunkbase * 8;
    srow[i2]  = p >> 3;
    skc[i2]   = (p & 7) ^ (srow[i2] & 7);
  }

  for (int tile = t_begin; tile < t_end; ++tile) {
    const int t0 = tile * 64;
    __syncthreads();
#pragma unroll
    for (int i2 = 0; i2 < 2; ++i2) {
      async_copy16(&Ks[sbase[i2]], kbase + (size_t)(t0 + srow[i2]) * HD + skc[i2] * 8);
      async_copy16(&Vs[sbase[i2]], vbase + (size_t)srow[i2] * S_LEN + t0 + skc[i2] * 8);
    }
    __syncthreads();

    const bool masked = (tile == T - 1);
    int nact = 4;
    if (masked) { nact = ((s0 + 31 - t0) >> 4) + 1; if (nact > 4) nact = 4; }
    const int nkh = (nact + 1) >> 1;

    // S^T = mfma(A=K, B=Q): D[m=key_local=quad*4+reg][n=qrow=c]
#pragma unroll
    for (int rf = 0; rf < 2; ++rf) {
      for (int kt2 = 0; kt2 < nact; ++kt2) {
        f32x4 st = {};
#pragma unroll
        for (int ks = 0; ks < 2; ++ks) {
          bf16x8 kf = *(const bf16x8*)&Ks[((kt2 * 16 + c) * 8 + ((ks * 4 + quad) ^ (c & 7))) * 8];
          st = __builtin_amdgcn_mfma_f32_16x16x32_bf16(kf, qf[rf][ks], st, 0, 0, 0);
        }
        const int row = s0 + rf * 16 + c;
        bf16x4 pk;
#pragma unroll
        for (int reg = 0; reg < 4; ++reg) {
          const int key = t0 + kt2 * 16 + quad * 4 + reg;
          float p = exp2f(st[reg] - EBIAS);
          if (masked && key > row) p = 0.f;
          pk[reg] = (bf16_t)p;
        }
        *(bf16x4*)&Ps[w][(rf * 16 + c) * PSTR + kt2 * 16 + quad * 4] = pk;
      }
      for (int kt2 = nact; kt2 < 2 * nkh; ++kt2) {
        bf16x4 z = {};
        *(bf16x4*)&Ps[w][(rf * 16 + c) * PSTR + kt2 * 16 + quad * 4] = z;
      }
    }

    // PV (+ row-sum via ones frag): A = P[m=qrow][k=key], B = V^T[n=d][k=key]
    for (int kh2 = 0; kh2 < nkh; ++kh2) {
      bf16x8 vf[4];
#pragma unroll
      for (int dt = 0; dt < 4; ++dt)
        vf[dt] = *(const bf16x8*)&Vs[((dt * 16 + c) * 8 + ((kh2 * 4 + quad) ^ (c & 7))) * 8];
#pragma unroll
      for (int rf = 0; rf < 2; ++rf) {
        bf16x8 pa = *(const bf16x8*)&Ps[w][(rf * 16 + c) * PSTR + kh2 * 32 + quad * 8];
#pragma unroll
        for (int dt = 0; dt < 4; ++dt)
          acc[rf][dt] = __builtin_amdgcn_mfma_f32_16x16x32_bf16(pa, vf[dt], acc[rf][dt], 0, 0, 0);
        accl[rf] = __builtin_amdgcn_mfma_f32_16x16x32_bf16(pa, onesf, accl[rf], 0, 0, 0);
      }
    }
  }

  if (i < 16) {
    // single-chunk entry: accl rows match acc rows exactly -> direct normalize.
#pragma unroll
    for (int rf = 0; rf < 2; ++rf)
#pragma unroll
      for (int reg = 0; reg < 4; ++reg) {
        const float inv = 1.0f / accl[rf][reg];
        const int row = s0 + rf * 16 + quad * 4 + reg;
#pragma unroll
        for (int dt = 0; dt < 4; ++dt)
          attn[(size_t)row * H_DIM + h * HD + dt * 16 + c] = (bf16_t)(acc[rf][dt][reg] * inv);
      }
  } else {
    float* ent = pbuf + (size_t)e * ENT_STRIDE;
#pragma unroll
    for (int rf = 0; rf < 2; ++rf) {
#pragma unroll
      for (int dt = 0; dt < 4; ++dt)
#pragma unroll
        for (int reg = 0; reg < 4; ++reg)
          ent[w * 2048 + (rf * 16 + quad * 4 + reg) * 64 + dt * 16 + c] = acc[rf][dt][reg];
      if (c == 0)
        *(f32x4*)&ent[8192 + w * 32 + rf * 16 + quad * 4] = accl[rf];
    }
  }
}

// ---------------- reduce: sum chunks (qt>=16), normalize, write bf16 attn ----------------
__global__ __launch_bounds__(256) void flash_reduce(const float* __restrict__ pbuf,
                                                    bf16_t* __restrict__ attn) {
  const int kh = blockIdx.x / 48;
  const int qt = 16 + (blockIdx.x % 48);
  const int b  = qt >> 4;
  int base;
  if (b == 1)      base = kh * 160 + 16 + (qt - 16) * 2;
  else if (b == 2) base = kh * 160 + 48 + (qt - 32) * 3;
  else             base = kh * 160 + 96 + (qt - 48) * 4;
  const int nch = b + 1;

  const int t   = threadIdx.x;
  const int h2  = t >> 6;
  const int row = (t >> 1) & 31;
  const int dh  = t & 1;

  f32x4 o[8] = {};
  float l = 0.f;
  for (int ci = 0; ci < nch; ++ci) {
    const float* ent = pbuf + (size_t)(base + ci) * ENT_STRIDE;
    const float* p = ent + h2 * 2048 + row * 64 + dh * 32;
#pragma unroll
    for (int j = 0; j < 8; ++j) {
      f32x4 v = ((const f32x4*)p)[j];
      o[j][0] += v[0]; o[j][1] += v[1]; o[j][2] += v[2]; o[j][3] += v[3];
    }
    l += ent[8192 + h2 * 32 + row];
  }
  const float inv = 1.0f / l;
  bf16_t* dst = attn + (size_t)(qt * 32 + row) * H_DIM + (kh * 4 + h2) * 64 + dh * 32;
#pragma unroll
  for (int j = 0; j < 8; ++j) {
    bf16x4 ov;
    ov[0] = (bf16_t)(o[j][0] * inv); ov[1] = (bf16_t)(o[j][1] * inv);
    ov[2] = (bf16_t)(o[j][2] * inv); ov[3] = (bf16_t)(o[j][3] * inv);
    *(bf16x4*)(dst + j * 4) = ov;
  }
}

// ---------------- launch ----------------
extern "C" void kernel_launch(void* const* d_in, const int* in_sizes, int n_in,
                              void* d_out, int out_size, void* d_ws, size_t ws_size,
                              hipStream_t stream) {
  const float* x     = (const float*)d_in[0];
  const float* w_qkv = (const float*)d_in[1];
  const float* w_o   = (const float*)d_in[2];
  float* out = (float*)d_out;

  char* ws = (char*)d_ws;
  const size_t OVERLAY = (size_t)1280 * ENT_STRIDE * 4;  // 42.6 MB
  bf16_t* x_bf    = (bf16_t*)ws;
  bf16_t* wqkv_bf = (bf16_t*)(ws + (size_t)S_LEN * H_DIM * 2);
  float*  pbuf    = (float*)ws;
  size_t off = OVERLAY;
  bf16_t* wo_bf   = (bf16_t*)(ws + off); off += (size_t)H_DIM * H_DIM * 2;
  bf16_t* q_bf    = (bf16_t*)(ws + off); off += (size_t)S_LEN * H_DIM * 2;
  bf16_t* k_t     = (bf16_t*)(ws + off); off += (size_t)KVH * S_LEN * HD * 2;
  bf16_t* v_t2    = (bf16_t*)(ws + off); off += (size_t)KVH * S_LEN * HD * 2;
  bf16_t* attn    = (bf16_t*)(ws + off); off += (size_t)S_LEN * H_DIM * 2;

  const int ntot = (S_LEN * H_DIM + QKV_N * H_DIM + H_DIM * H_DIM) / 4;
  cast3_kernel<<<(ntot + 255) / 256, 256, 0, stream>>>(x, w_qkv, w_o, x_bf, wqkv_bf, wo_bf);

  gemm_sk<1><<<dim3(QKV_N / GBN, S_LEN / GBM), 512, 0, stream>>>(
      x_bf, wqkv_bf, nullptr, q_bf, k_t, v_t2, S_LEN, QKV_N, H_DIM);

  flash_split<<<1280, 256, 0, stream>>>(q_bf, k_t, v_t2, pbuf, attn);
  flash_reduce<<<384, 256, 0, stream>>>(pbuf, attn);

  gemm_sk<0><<<dim3(H_DIM / GBN, S_LEN / GBM), 512, 0, stream>>>(
      attn, wo_bf, out, nullptr, nullptr, nullptr, S_LEN, H_DIM, H_DIM);
}